// Round 15
// baseline (225.695 us; speedup 1.0000x reference)
//
#include <hip/hip_runtime.h>
#include <hip/hip_bf16.h>

#define N_TOK 8192
#define DIM   2048
#define NEXP  8
#define BM    288          // sum ceil(c_e/288) == 32 for c_e in [865,1152]
#define BN    128          // 16 col-tiles -> ttot = 512 = exactly 2 tiles/CU
#define BK    32
#define NT    (DIM / BK)   // 64 K-steps
#define NBLK  512          // 2 blocks per CU

#define A_BYTES  (BM * BK * 2)            // 18432 (A: bf16 in LDS; B never touches LDS)
#define RING     A_BYTES
#define DYN_LDS  (2 * RING)               // 36864 (ring-2)

typedef __attribute__((ext_vector_type(8))) short  short8;
typedef __attribute__((ext_vector_type(4))) float  f32x4;
typedef __attribute__((ext_vector_type(4))) unsigned int u32x4;

static __device__ __forceinline__ unsigned int pack_bf2(float a, float b) {
  union { __hip_bfloat16 h; unsigned short u; } ca, cb;
  ca.h = __float2bfloat16(a);
  cb.h = __float2bfloat16(b);
  return ((unsigned int)cb.u << 16) | (unsigned int)ca.u;
}

static __device__ __forceinline__ void gload16(const void* g, void* l) {
  __builtin_amdgcn_global_load_lds(
      (const __attribute__((address_space(1))) unsigned int*)g,
      (__attribute__((address_space(3))) unsigned int*)l, 16, 0, 0);
}

static __device__ __forceinline__ double dot8d(const float4& x0, const float4& x1,
                                               const float4& w0, const float4& w1) {
  double a = 0.0;
  a = fma((double)x0.x, (double)w0.x, a);
  a = fma((double)x0.y, (double)w0.y, a);
  a = fma((double)x0.z, (double)w0.z, a);
  a = fma((double)x0.w, (double)w0.w, a);
  a = fma((double)x1.x, (double)w1.x, a);
  a = fma((double)x1.y, (double)w1.y, a);
  a = fma((double)x1.z, (double)w1.z, a);
  a = fma((double)x1.w, (double)w1.w, a);
  return a;
}

// ---------------- router (unchanged, round 8) ----------------
__global__ __launch_bounds__(256, 3) void router_kernel(
    const float* __restrict__ x, const float* __restrict__ rw,
    const float* __restrict__ rb, int* __restrict__ eid,
    float* __restrict__ gate, unsigned short* __restrict__ xb)
{
  const int t    = threadIdx.x;
  const int tok0 = blockIdx.x * 4;

  float4 w0[NEXP], w1[NEXP];
#pragma unroll
  for (int e = 0; e < NEXP; e++) {
    const float4* wr = reinterpret_cast<const float4*>(rw + (size_t)e * DIM);
    w0[e] = wr[2 * t];
    w1[e] = wr[2 * t + 1];
  }
  float4 xv0[4], xv1[4];
#pragma unroll
  for (int k = 0; k < 4; k++) {
    const float4* xr = reinterpret_cast<const float4*>(x + (size_t)(tok0 + k) * DIM);
    xv0[k] = xr[2 * t];
    xv1[k] = xr[2 * t + 1];
  }
#pragma unroll
  for (int k = 0; k < 4; k++) {
    u32x4 pk;
    pk[0] = pack_bf2(xv0[k].x, xv0[k].y); pk[1] = pack_bf2(xv0[k].z, xv0[k].w);
    pk[2] = pack_bf2(xv1[k].x, xv1[k].y); pk[3] = pack_bf2(xv1[k].z, xv1[k].w);
    *reinterpret_cast<u32x4*>(xb + (size_t)(tok0 + k) * DIM + t * 8) = pk;
  }

  __shared__ double red[4][4][NEXP];
  const int lane = t & 63, wv = t >> 6;
#pragma unroll
  for (int k = 0; k < 4; k++) {
    double s[NEXP];
#pragma unroll
    for (int e = 0; e < NEXP; e++) s[e] = dot8d(xv0[k], xv1[k], w0[e], w1[e]);
#pragma unroll
    for (int e = 0; e < NEXP; e++) {
      double v = s[e];
#pragma unroll
      for (int off = 32; off > 0; off >>= 1) v += __shfl_xor(v, off, 64);
      if (lane == 0) red[wv][k][e] = v;
    }
  }
  __syncthreads();
  if (t < 4) {
    double lg[NEXP];
    double lmax = -1e300; int best = 0;
#pragma unroll
    for (int e = 0; e < NEXP; e++) {
      lg[e] = red[0][t][e] + red[1][t][e] + red[2][t][e] + red[3][t][e] + (double)rb[e];
      if (lg[e] > lmax) { lmax = lg[e]; best = e; }   // strict > == first-occurrence argmax
    }
    float den = 0.f;
#pragma unroll
    for (int e = 0; e < NEXP; e++) den += expf((float)(lg[e] - lmax));
    eid[tok0 + t]  = best;
    gate[tok0 + t] = 1.0f / den;
  }
}

// ---------------- histo + permute (unchanged, round 14) ----------------
__global__ __launch_bounds__(1024) void histo_perm(
    const int* __restrict__ eid, int* __restrict__ counts, int* __restrict__ perm,
    float* __restrict__ out)
{
  __shared__ int hist[NEXP], baseS[NEXP], fillS[NEXP];
  const int t = threadIdx.x;
  if (t < NEXP) { hist[t] = 0; fillS[t] = 0; }
  if (t == 64) out[(size_t)N_TOK * DIM] = 0.0f;    // loss output
  __syncthreads();
  int my[8];
#pragma unroll
  for (int i = 0; i < 8; i++) {
    my[i] = eid[t + i * 1024];
    atomicAdd(&hist[my[i]], 1);
  }
  __syncthreads();
  if (t == 0) {
    int b = 0;
#pragma unroll
    for (int e = 0; e < NEXP; e++) { counts[e] = hist[e]; baseS[e] = b; b += hist[e]; }
  }
  __syncthreads();
#pragma unroll
  for (int i = 0; i < 8; i++) {
    int pos = baseS[my[i]] + atomicAdd(&fillS[my[i]], 1);
    perm[pos] = t + i * 1024;
  }
}

// ------- grouped GEMM: A-only LDS (ring-2), B fp32 global->reg->cvt (no LDS) ---------
// LDS volume halved vs r14 (54 vs 118 KB/block-step); B regs are compiler-tracked
// (auto-waitcnt before the cvt), live range ends before the MFMA cluster -> no spill.
// A publish discipline: vmcnt(0) [A(t) issued a full step earlier -> ~free] -> barrier.
// B's 16-rows x 8-col-chunk global pattern == the ds_read_b128 shape, fully coalesced.
__global__ __launch_bounds__(256, 2) void moe_gemm(
    const unsigned short* __restrict__ xb, const float* __restrict__ ew,
    const float* __restrict__ eb, const float* __restrict__ gate,
    const int* __restrict__ perm, const int* __restrict__ counts,
    float* __restrict__ out)
{
  extern __shared__ char smem[];     // 2 ring slots of A (18432 B bf16 each)
  __shared__ int   aRowS[BM];
  __shared__ float gateS[BM];

  const int tid  = threadIdx.x;
  const int lane = tid & 63, wid = tid >> 6;   // 4 waves

  int ttot = 0;
#pragma unroll
  for (int j = 0; j < NEXP; j++) ttot += (counts[j] + BM - 1) / BM;
  ttot *= 16;                                   // 16 col-tiles
  const int tq = ttot >> 3, tr = ttot & 7;

  // ---- A staging geometry: 18 chunks of 16 rows x 64B; waves 0-1: 5, waves 2-3: 4 ----
  const int nA5 = (wid < 2);
  int aC[5];
#pragma unroll
  for (int i = 0; i < 5; i++)
    aC[i] = (wid < 2) ? (wid * 5 + i) : (10 + (wid - 2) * 4 + ((i < 4) ? i : 0));
  int aDst[5];
#pragma unroll
  for (int i = 0; i < 5; i++) aDst[i] = aC[i] * 1024;
  const int lrowA = lane >> 2;                          // row within 16-row chunk
  const int cblkA = (lane & 3) ^ ((lane >> 3) & 3);     // pre-swizzled src (involution)

  // ---- MFMA fragment addressing (2M x 2N waves; per-wave 144x64 output) ----
  const int l15 = lane & 15;
  const int wr = wid >> 1, wc = wid & 1;
  const int swA  = (((lane >> 4) ^ ((l15 >> 1) & 3)) * 16);   // A read-side swizzle
  const int aOff = (wr * 144 + l15) * 64 + swA;
  const int rsub = (lane >> 4) * 4;

  for (int ti = blockIdx.x; ti < ttot; ti += NBLK) {
    // ---- m204 bijective XCD remap: XCD k = ti&7 owns contiguous bx-major range ----
    const int k  = ti & 7, j = ti >> 3;
    const int tt = k * tq + (k < tr ? k : tr) + j;     // logical tile (bx-major)
    const int bx = tt >> 4, by = tt & 15;

    int e = 0, rowbase = 0, nrows = 0, found = 0;
    {
      int tsum = 0, bsum = 0;
#pragma unroll
      for (int jj = 0; jj < NEXP; jj++) {
        int cj = counts[jj];
        int te = (cj + BM - 1) / BM;
        if (!found && bx < tsum + te) {
          int loc = bx - tsum;
          e = jj;
          rowbase = bsum + loc * BM;
          int rem = cj - loc * BM;
          nrows = rem < BM ? rem : BM;
          found = 1;
        }
        tsum += te; bsum += cj;
      }
    }

    __syncthreads();   // prior tile fully done with aRowS/gateS and LDS slots
    for (int r = tid; r < BM; r += 256) {
      int idx = r < nrows ? r : (nrows - 1);
      int tok = perm[rowbase + idx];
      aRowS[r] = tok;
      gateS[r] = gate[tok];
    }
    __syncthreads();

    const unsigned short* aSrc[5];
#pragma unroll
    for (int i = 0; i < 5; i++)
      aSrc[i] = xb + (size_t)aRowS[aC[i] * 16 + lrowA] * DIM + cblkA * 8;

    // ---- B: direct global fp32 pointers; lane l15 -> row, lane>>4 -> 8-col chunk ----
    const float* wB32 = ew + (size_t)e * DIM * DIM;
    const float* bp[4];
#pragma unroll
    for (int n = 0; n < 4; n++)
      bp[n] = wB32 + (size_t)(by * BN + wc * 64 + n * 16 + l15) * DIM + (lane >> 4) * 8;

#define ASTAGE(SLOTP)                                                       \
    do {                                                                    \
      char* sb_ = (SLOTP);                                                  \
      gload16(aSrc[0], sb_ + aDst[0]);                                      \
      gload16(aSrc[1], sb_ + aDst[1]);                                      \
      gload16(aSrc[2], sb_ + aDst[2]);                                      \
      gload16(aSrc[3], sb_ + aDst[3]);                                      \
      if (nA5) gload16(aSrc[4], sb_ + aDst[4]);                             \
      aSrc[0] += BK; aSrc[1] += BK; aSrc[2] += BK; aSrc[3] += BK;           \
      aSrc[4] += BK;                                                        \
    } while (0)

    ASTAGE(smem);                     // stage A K-step 0 into slot 0

    f32x4 acc[9][4] = {};

#pragma unroll 1
    for (int t = 0; t < NT; ++t) {
      // A(t) loads were issued one full step ago -> drain ~free; publish slot t
      asm volatile("s_waitcnt vmcnt(0)" ::: "memory");
      __builtin_amdgcn_s_barrier();

      if (t + 1 < NT) ASTAGE(smem + (size_t)((t + 1) & 1) * RING);

      // ---- B: fp32 global->reg (compiler-tracked waits), cvt to bf16 ----
      f32x4 r0[4], r1[4];
#pragma unroll
      for (int n = 0; n < 4; n++) {
        r0[n] = *(const f32x4*)(bp[n]);
        r1[n] = *(const f32x4*)(bp[n] + 4);
        bp[n] += BK;
      }
      // ---- A: bf16 ds_read frags ----
      const char* cur = smem + (size_t)(t & 1) * RING;
      short8 af[9];
#pragma unroll
      for (int m = 0; m < 9; m++) af[m] = *(const short8*)(cur + aOff + m * 1024);

      short8 bf[4];
#pragma unroll
      for (int n = 0; n < 4; n++) {
        u32x4 pk;
        pk[0] = pack_bf2(r0[n][0], r0[n][1]);
        pk[1] = pack_bf2(r0[n][2], r0[n][3]);
        pk[2] = pack_bf2(r1[n][0], r1[n][1]);
        pk[3] = pack_bf2(r1[n][2], r1[n][3]);
        union { u32x4 u; short8 s; } cv;
        cv.u = pk;
        bf[n] = cv.s;
      }

      __builtin_amdgcn_s_setprio(1);
#pragma unroll
      for (int m = 0; m < 9; m++)
#pragma unroll
        for (int n = 0; n < 4; n++)
          acc[m][n] = __builtin_amdgcn_mfma_f32_16x16x32_bf16(af[m], bf[n], acc[m][n], 0, 0, 0);
      __builtin_amdgcn_s_setprio(0);
    }
#undef ASTAGE

    // ---- epilogue: +bias, *gate, scatter by token ----
    const int cb = by * BN + wc * 64;
    const float* ebE = eb + (size_t)e * DIM;
    float bias[4];
#pragma unroll
    for (int n = 0; n < 4; n++) bias[n] = ebE[cb + n * 16 + l15];
#pragma unroll
    for (int m = 0; m < 9; m++) {
      int r0w = wr * 144 + m * 16 + rsub;
#pragma unroll
      for (int rg = 0; rg < 4; rg++) {
        int r = r0w + rg;
        if (r < nrows) {
          float g = gateS[r];
          float* orow = out + (size_t)aRowS[r] * DIM + cb;
#pragma unroll
          for (int n = 0; n < 4; n++)
            orow[n * 16 + l15] = (acc[m][n][rg] + bias[n]) * g;
        }
      }
    }
    asm volatile("s_waitcnt vmcnt(0)" ::: "memory");   // drain stores before next tile
  }
}

extern "C" void kernel_launch(void* const* d_in, const int* in_sizes, int n_in,
                              void* d_out, int out_size, void* d_ws, size_t ws_size,
                              hipStream_t stream)
{
  const float* x  = (const float*)d_in[0];
  const float* ew = (const float*)d_in[1];
  const float* eb = (const float*)d_in[2];
  const float* rw = (const float*)d_in[3];
  const float* rb = (const float*)d_in[4];
  float* out = (float*)d_out;

  char* ws = (char*)d_ws;
  int*   eid    = (int*)(ws);                  // 8192 ints
  float* gate   = (float*)(ws + 32 * 1024);    // 8192 floats
  int*   counts = (int*)(ws + 64 * 1024);      // [0..7]
  int*   perm   = (int*)(ws + 128 * 1024);     // 8192 ints
  unsigned short* xbuf = (unsigned short*)(ws + 192 * 1024);   // 32 MB

  hipFuncSetAttribute(reinterpret_cast<const void*>(moe_gemm),
                      hipFuncAttributeMaxDynamicSharedMemorySize, DYN_LDS);

  router_kernel<<<N_TOK / 4, 256, 0, stream>>>(x, rw, rb, eid, gate, xbuf);
  histo_perm<<<1, 1024, 0, stream>>>(eid, counts, perm, out);
  moe_gemm<<<NBLK, 256, DYN_LDS, stream>>>(xbuf, ew, eb, gate, perm, counts, out);
}

// Round 16
// 155.098 us; speedup vs baseline: 1.4552x; 1.4552x over previous
//
#include <hip/hip_runtime.h>
#include <hip/hip_bf16.h>

#define N_TOK 8192
#define DIM   2048
#define NEXP  8
#define BM    288          // sum ceil(c_e/288) == 32 for c_e in [865,1152]
#define BN    128          // 16 col-tiles -> ttot = 512 = exactly 2 tiles/CU
#define BK    32
#define NT    (DIM / BK)   // 64 K-steps
#define NBLK  512          // 2 blocks per CU

#define A_BYTES  (BM * BK * 2)            // 18432 (A: bf16, via global_load_lds)
#define B_BYTES  (BN * BK * 2)            // 8192  (B: bf16, cvt-at-write via ds_write)
#define RING     (A_BYTES + B_BYTES)      // 26624
#define DYN_LDS  (2 * RING)               // 53248 (ring-2; 2 blocks/CU = 106KB < 160KB)

typedef __attribute__((ext_vector_type(8))) short  short8;
typedef __attribute__((ext_vector_type(4))) float  f32x4;
typedef __attribute__((ext_vector_type(4))) unsigned int u32x4;

static __device__ __forceinline__ unsigned int pack_bf2(float a, float b) {
  union { __hip_bfloat16 h; unsigned short u; } ca, cb;
  ca.h = __float2bfloat16(a);
  cb.h = __float2bfloat16(b);
  return ((unsigned int)cb.u << 16) | (unsigned int)ca.u;
}

static __device__ __forceinline__ void gload16(const void* g, void* l) {
  __builtin_amdgcn_global_load_lds(
      (const __attribute__((address_space(1))) unsigned int*)g,
      (__attribute__((address_space(3))) unsigned int*)l, 16, 0, 0);
}

static __device__ __forceinline__ double dot8d(const float4& x0, const float4& x1,
                                               const float4& w0, const float4& w1) {
  double a = 0.0;
  a = fma((double)x0.x, (double)w0.x, a);
  a = fma((double)x0.y, (double)w0.y, a);
  a = fma((double)x0.z, (double)w0.z, a);
  a = fma((double)x0.w, (double)w0.w, a);
  a = fma((double)x1.x, (double)w1.x, a);
  a = fma((double)x1.y, (double)w1.y, a);
  a = fma((double)x1.z, (double)w1.z, a);
  a = fma((double)x1.w, (double)w1.w, a);
  return a;
}

// ---------------- router (unchanged, round 8) ----------------
__global__ __launch_bounds__(256, 3) void router_kernel(
    const float* __restrict__ x, const float* __restrict__ rw,
    const float* __restrict__ rb, int* __restrict__ eid,
    float* __restrict__ gate, unsigned short* __restrict__ xb)
{
  const int t    = threadIdx.x;
  const int tok0 = blockIdx.x * 4;

  float4 w0[NEXP], w1[NEXP];
#pragma unroll
  for (int e = 0; e < NEXP; e++) {
    const float4* wr = reinterpret_cast<const float4*>(rw + (size_t)e * DIM);
    w0[e] = wr[2 * t];
    w1[e] = wr[2 * t + 1];
  }
  float4 xv0[4], xv1[4];
#pragma unroll
  for (int k = 0; k < 4; k++) {
    const float4* xr = reinterpret_cast<const float4*>(x + (size_t)(tok0 + k) * DIM);
    xv0[k] = xr[2 * t];
    xv1[k] = xr[2 * t + 1];
  }
#pragma unroll
  for (int k = 0; k < 4; k++) {
    u32x4 pk;
    pk[0] = pack_bf2(xv0[k].x, xv0[k].y); pk[1] = pack_bf2(xv0[k].z, xv0[k].w);
    pk[2] = pack_bf2(xv1[k].x, xv1[k].y); pk[3] = pack_bf2(xv1[k].z, xv1[k].w);
    *reinterpret_cast<u32x4*>(xb + (size_t)(tok0 + k) * DIM + t * 8) = pk;
  }

  __shared__ double red[4][4][NEXP];
  const int lane = t & 63, wv = t >> 6;
#pragma unroll
  for (int k = 0; k < 4; k++) {
    double s[NEXP];
#pragma unroll
    for (int e = 0; e < NEXP; e++) s[e] = dot8d(xv0[k], xv1[k], w0[e], w1[e]);
#pragma unroll
    for (int e = 0; e < NEXP; e++) {
      double v = s[e];
#pragma unroll
      for (int off = 32; off > 0; off >>= 1) v += __shfl_xor(v, off, 64);
      if (lane == 0) red[wv][k][e] = v;
    }
  }
  __syncthreads();
  if (t < 4) {
    double lg[NEXP];
    double lmax = -1e300; int best = 0;
#pragma unroll
    for (int e = 0; e < NEXP; e++) {
      lg[e] = red[0][t][e] + red[1][t][e] + red[2][t][e] + red[3][t][e] + (double)rb[e];
      if (lg[e] > lmax) { lmax = lg[e]; best = e; }   // strict > == first-occurrence argmax
    }
    float den = 0.f;
#pragma unroll
    for (int e = 0; e < NEXP; e++) den += expf((float)(lg[e] - lmax));
    eid[tok0 + t]  = best;
    gate[tok0 + t] = 1.0f / den;
  }
}

// ---------------- histo + permute (unchanged, round 14) ----------------
__global__ __launch_bounds__(1024) void histo_perm(
    const int* __restrict__ eid, int* __restrict__ counts, int* __restrict__ perm,
    float* __restrict__ out)
{
  __shared__ int hist[NEXP], baseS[NEXP], fillS[NEXP];
  const int t = threadIdx.x;
  if (t < NEXP) { hist[t] = 0; fillS[t] = 0; }
  if (t == 64) out[(size_t)N_TOK * DIM] = 0.0f;    // loss output
  __syncthreads();
  int my[8];
#pragma unroll
  for (int i = 0; i < 8; i++) {
    my[i] = eid[t + i * 1024];
    atomicAdd(&hist[my[i]], 1);
  }
  __syncthreads();
  if (t == 0) {
    int b = 0;
#pragma unroll
    for (int e = 0; e < NEXP; e++) { counts[e] = hist[e]; baseS[e] = b; b += hist[e]; }
  }
  __syncthreads();
#pragma unroll
  for (int i = 0; i < 8; i++) {
    int pos = baseS[my[i]] + atomicAdd(&fillS[my[i]], 1);
    perm[pos] = t + i * 1024;
  }
}

// ------- grouped GEMM: A bf16 gload_lds; B fp32 gread -> cvt -> bf16 ds_write --------
// B pipelined one step ahead THROUGH LDS (fixes r15's exposed latency) at bf16 cost
// (fixes r14's 4x LDS volume).  Per step t:
//   vmcnt(0) [A(t) issued last step -> free] -> barrier [publish A(t) gloads + B(t)
//   ds_writes] -> gread B(t+1) fp32 -> gload_lds A(t+1) -> ds_read A(t),B(t) -> MFMA
//   -> cvt B(t+1) [auto vmcnt(#A-gloads): A prefetch stays in flight] -> ds_write ->
//   lgkmcnt(0).
// B staging regs: 16 VGPR live across MFMA (4 waves, BN=128) -- half r11's load.
__global__ __launch_bounds__(256, 2) void moe_gemm(
    const unsigned short* __restrict__ xb, const float* __restrict__ ew,
    const float* __restrict__ eb, const float* __restrict__ gate,
    const int* __restrict__ perm, const int* __restrict__ counts,
    float* __restrict__ out)
{
  extern __shared__ char smem[];     // 2 ring slots of {A 18432 bf16 | B 8192 bf16}
  __shared__ int   aRowS[BM];
  __shared__ float gateS[BM];

  const int tid  = threadIdx.x;
  const int lane = tid & 63, wid = tid >> 6;   // 4 waves

  int ttot = 0;
#pragma unroll
  for (int j = 0; j < NEXP; j++) ttot += (counts[j] + BM - 1) / BM;
  ttot *= 16;                                   // 16 col-tiles
  const int tq = ttot >> 3, tr = ttot & 7;

  // ---- A staging geometry: 18 chunks of 16 rows x 64B; waves 0-1: 5, waves 2-3: 4 ----
  const int nA5 = (wid < 2);
  int aC[5];
#pragma unroll
  for (int i = 0; i < 5; i++)
    aC[i] = (wid < 2) ? (wid * 5 + i) : (10 + (wid - 2) * 4 + ((i < 4) ? i : 0));
  int aDst[5];
#pragma unroll
  for (int i = 0; i < 5; i++) aDst[i] = aC[i] * 1024;
  const int lrowA = lane >> 2;                          // row within 16-row chunk
  const int cblkA = (lane & 3) ^ ((lane >> 3) & 3);     // pre-swizzled src (involution)

  // ---- B staging geometry: lane -> (rowW, half); 32 rows/wave, 2 lanes/row ----
  const int rowW = wid * 32 + (lane >> 1);              // B LDS row (= output col)
  const int hB   = lane & 1;                            // which 16-float half of BK
  const int sW   = (rowW >> 1) & 3;                     // write-side XOR swizzle key
  const int bWr0 = A_BYTES + rowW * 64 + (((2 * hB)     ^ sW) << 4);
  const int bWr1 = A_BYTES + rowW * 64 + (((2 * hB + 1) ^ sW) << 4);

  // ---- MFMA fragment addressing (2M x 2N waves; per-wave 144x64 output) ----
  const int l15 = lane & 15;
  const int wr = wid >> 1, wc = wid & 1;
  const int swA  = (((lane >> 4) ^ ((l15 >> 1) & 3)) * 16);   // read-side swizzle
  const int aOff = (wr * 144 + l15) * 64 + swA;
  int bOffN[4];
#pragma unroll
  for (int n = 0; n < 4; n++) {
    int row = wc * 64 + n * 16 + l15;
    bOffN[n] = A_BYTES + row * 64 + ((((lane >> 4) ^ ((row >> 1) & 3))) << 4);
  }
  const int rsub = (lane >> 4) * 4;

  for (int ti = blockIdx.x; ti < ttot; ti += NBLK) {
    // ---- m204 bijective XCD remap: XCD k = ti&7 owns contiguous bx-major range ----
    const int k  = ti & 7, j = ti >> 3;
    const int tt = k * tq + (k < tr ? k : tr) + j;     // logical tile (bx-major)
    const int bx = tt >> 4, by = tt & 15;

    int e = 0, rowbase = 0, nrows = 0, found = 0;
    {
      int tsum = 0, bsum = 0;
#pragma unroll
      for (int jj = 0; jj < NEXP; jj++) {
        int cj = counts[jj];
        int te = (cj + BM - 1) / BM;
        if (!found && bx < tsum + te) {
          int loc = bx - tsum;
          e = jj;
          rowbase = bsum + loc * BM;
          int rem = cj - loc * BM;
          nrows = rem < BM ? rem : BM;
          found = 1;
        }
        tsum += te; bsum += cj;
      }
    }

    __syncthreads();   // prior tile fully done with aRowS/gateS and LDS slots
    for (int r = tid; r < BM; r += 256) {
      int idx = r < nrows ? r : (nrows - 1);
      int tok = perm[rowbase + idx];
      aRowS[r] = tok;
      gateS[r] = gate[tok];
    }
    __syncthreads();

    const unsigned short* aSrc[5];
#pragma unroll
    for (int i = 0; i < 5; i++)
      aSrc[i] = xb + (size_t)aRowS[aC[i] * 16 + lrowA] * DIM + cblkA * 8;

    const float* wB32 = ew + (size_t)e * DIM * DIM;
    const float* bp = wB32 + (size_t)(by * BN + rowW) * DIM + hB * 16;

#define ASTAGE(SLOTP)                                                       \
    do {                                                                    \
      char* sb_ = (SLOTP);                                                  \
      gload16(aSrc[0], sb_ + aDst[0]);                                      \
      gload16(aSrc[1], sb_ + aDst[1]);                                      \
      gload16(aSrc[2], sb_ + aDst[2]);                                      \
      gload16(aSrc[3], sb_ + aDst[3]);                                      \
      if (nA5) gload16(aSrc[4], sb_ + aDst[4]);                             \
      aSrc[0] += BK; aSrc[1] += BK; aSrc[2] += BK; aSrc[3] += BK;           \
      aSrc[4] += BK;                                                        \
    } while (0)

#define BGREAD(BW)                                                          \
    do {                                                                    \
      BW[0] = *(const f32x4*)(bp);                                          \
      BW[1] = *(const f32x4*)(bp + 4);                                      \
      BW[2] = *(const f32x4*)(bp + 8);                                      \
      BW[3] = *(const f32x4*)(bp + 12);                                     \
      bp += BK;                                                             \
    } while (0)

#define BCVTWRITE(BW, SLOTP)                                                \
    do {                                                                    \
      char* sb_ = (SLOTP);                                                  \
      u32x4 p0, p1;                                                         \
      p0[0] = pack_bf2(BW[0][0], BW[0][1]); p0[1] = pack_bf2(BW[0][2], BW[0][3]); \
      p0[2] = pack_bf2(BW[1][0], BW[1][1]); p0[3] = pack_bf2(BW[1][2], BW[1][3]); \
      p1[0] = pack_bf2(BW[2][0], BW[2][1]); p1[1] = pack_bf2(BW[2][2], BW[2][3]); \
      p1[2] = pack_bf2(BW[3][0], BW[3][1]); p1[3] = pack_bf2(BW[3][2], BW[3][3]); \
      *reinterpret_cast<u32x4*>(sb_ + bWr0) = p0;                           \
      *reinterpret_cast<u32x4*>(sb_ + bWr1) = p1;                           \
    } while (0)

    // ---- prologue: B(0) gread->cvt->write slot0; A(0) gload slot0 ----
    f32x4 bw[4];
    BGREAD(bw);                       // oldest in VMEM queue
    ASTAGE(smem);                     // A(0)
    BCVTWRITE(bw, smem);              // auto-vmcnt waits B greads (A stays in flight)
    asm volatile("s_waitcnt lgkmcnt(0)" ::: "memory");

    f32x4 acc[9][4] = {};

#pragma unroll 1
    for (int t = 0; t < NT; ++t) {
      // A(t) gloads issued last step -> drain ~free; barrier publishes A(t)+B(t)
      asm volatile("s_waitcnt vmcnt(0)" ::: "memory");
      __builtin_amdgcn_s_barrier();

      const bool pf = (t + 1 < NT);
      char* nxt = smem + (size_t)((t + 1) & 1) * RING;
      if (pf) {
        BGREAD(bw);                   // B(t+1) fp32 -> regs (issued first = oldest)
        ASTAGE(nxt);                  // A(t+1) -> LDS
      }

      const char* cur = smem + (size_t)(t & 1) * RING;
      short8 af[9], bf[4];
#pragma unroll
      for (int n = 0; n < 4; n++) bf[n] = *(const short8*)(cur + bOffN[n]);
#pragma unroll
      for (int m = 0; m < 9; m++) af[m] = *(const short8*)(cur + aOff + m * 1024);

      __builtin_amdgcn_s_setprio(1);
#pragma unroll
      for (int m = 0; m < 9; m++)
#pragma unroll
        for (int n = 0; n < 4; n++)
          acc[m][n] = __builtin_amdgcn_mfma_f32_16x16x32_bf16(af[m], bf[n], acc[m][n], 0, 0, 0);
      __builtin_amdgcn_s_setprio(0);

      if (pf) {
        BCVTWRITE(bw, nxt);           // cvt auto-waits B(t+1) greads only
        asm volatile("s_waitcnt lgkmcnt(0)" ::: "memory");
      }
    }
#undef ASTAGE
#undef BGREAD
#undef BCVTWRITE

    // ---- epilogue: +bias, *gate, scatter by token ----
    const int cb = by * BN + wc * 64;
    const float* ebE = eb + (size_t)e * DIM;
    float bias[4];
#pragma unroll
    for (int n = 0; n < 4; n++) bias[n] = ebE[cb + n * 16 + l15];
#pragma unroll
    for (int m = 0; m < 9; m++) {
      int r0w = wr * 144 + m * 16 + rsub;
#pragma unroll
      for (int rg = 0; rg < 4; rg++) {
        int r = r0w + rg;
        if (r < nrows) {
          float g = gateS[r];
          float* orow = out + (size_t)aRowS[r] * DIM + cb;
#pragma unroll
          for (int n = 0; n < 4; n++)
            orow[n * 16 + l15] = (acc[m][n][rg] + bias[n]) * g;
        }
      }
    }
    asm volatile("s_waitcnt vmcnt(0)" ::: "memory");   // drain stores before next tile
  }
}

extern "C" void kernel_launch(void* const* d_in, const int* in_sizes, int n_in,
                              void* d_out, int out_size, void* d_ws, size_t ws_size,
                              hipStream_t stream)
{
  const float* x  = (const float*)d_in[0];
  const float* ew = (const float*)d_in[1];
  const float* eb = (const float*)d_in[2];
  const float* rw = (const float*)d_in[3];
  const float* rb = (const float*)d_in[4];
  float* out = (float*)d_out;

  char* ws = (char*)d_ws;
  int*   eid    = (int*)(ws);                  // 8192 ints
  float* gate   = (float*)(ws + 32 * 1024);    // 8192 floats
  int*   counts = (int*)(ws + 64 * 1024);      // [0..7]
  int*   perm   = (int*)(ws + 128 * 1024);     // 8192 ints
  unsigned short* xbuf = (unsigned short*)(ws + 192 * 1024);   // 32 MB

  hipFuncSetAttribute(reinterpret_cast<const void*>(moe_gemm),
                      hipFuncAttributeMaxDynamicSharedMemorySize, DYN_LDS);

  router_kernel<<<N_TOK / 4, 256, 0, stream>>>(x, rw, rb, eid, gate, xbuf);
  histo_perm<<<1, 1024, 0, stream>>>(eid, counts, perm, out);
  moe_gemm<<<NBLK, 256, DYN_LDS, stream>>>(xbuf, ew, eb, gate, perm, counts, out);
}